// Round 2
// baseline (421.117 us; speedup 1.0000x reference)
//
#include <hip/hip_runtime.h>
#include <hip/hip_bf16.h>
#include <cstdint>

typedef __bf16 bf16;
typedef __bf16 bf16x8 __attribute__((ext_vector_type(8)));
typedef float f32x4 __attribute__((ext_vector_type(4)));

#define E_TOT   262144
#define NNODE   512
#define NDIM    128
#define EDIM    64
#define GDIM    32
#define FIN     320
#define XD      352   // FIN + CTX(32)
#define H1D     256
#define OUTD    64
#define AHD     64
#define NHEADS  4
#define NSEG    4096
#define TE      48    // edges per block (4 blocks/CU) -- TE=32@6blk regressed (L2 thrash)

#define SX_STR  360   // 720B = 180 words, %32=20 -> 2-way alias (free)
#define SH_STR  264   // 528B = 132 words, %32=4  -> 2-way
#define SA_STR  72    // 144B = 36 words,  %32=4

// fp32 params block (floats). LN gamma/beta folded into weights in k_prep:
// b1' = b1 + beta^T W1 ; ab1' = ab1 + beta^T A1 ; W1T,A1T scaled by gamma.
#define PRM_B1  0     // 256
#define PRM_B2  256   // 64
#define PRM_A2  320   // 256 (raw A2, row-major [64][4])
#define PRM_AB1 576   // 64
#define PRM_AB2 640   // 4
#define PRM_TOT 644

// LDS layout (bytes). sX 48x360x2=34560; sH (48x264x2=25344) overlays sX head;
// sA (48x72x2=6912) overlays sX at 25600 (ends 32512 <= 34560).
#define SMEM_SX    0
#define SMEM_SA    25600
#define SMEM_A2T   34560   // float[256] = 1024 (A2 transposed [h][k], pre-scaled 1/8)
#define SMEM_SEG   35584   // int[48]    = 192
#define SMEM_TOT   35776   // x4 = 143104 <= 160K -> 4 blocks/CU

#define ZOFF 507           // k_prep blocks >= ZOFF zero denom+pooled
#define ZBLK 272           // 272 * 4096B = 1114112B = denom(64K) + pooled(1M)

__device__ __forceinline__ float siluf(float v) {
    return v * __builtin_amdgcn_rcpf(1.0f + __expf(-v));
}

__device__ __forceinline__ float ldf(const void* p, int i, bool isb) {
    return isb ? (float)((const bf16*)p)[i] : ((const float*)p)[i];
}

// Per-wave dtype probe: 1=bf16 data, 0=fp32 data. Reads first 256 u16 of nodes.
__device__ __forceinline__ bool probe_bf16(const void* nodes, int t) {
    const unsigned short* u16 = (const unsigned short*)nodes;
    int lane = t & 63;
    int pl = 0;
    #pragma unroll
    for (int i = 0; i < 4; i++) {
        unsigned short u = u16[lane * 4 + i];
        int expo = (u >> 7) & 0xFF;
        pl += (((u & 0x7FFF) == 0) || (expo >= 97 && expo <= 137)) ? 1 : 0;
    }
    #pragma unroll
    for (int m = 1; m < 64; m <<= 1) pl += __shfl_xor(pl, m);
    return pl >= 240;
}

// ---------------- K_prep: gamma-folded weight transpose + bias fold + zero ----------------
__global__ __launch_bounds__(256) void k_prep(
    const void* __restrict__ nodes,
    const void* __restrict__ W1, const void* __restrict__ W2, const void* __restrict__ A1,
    const void* __restrict__ ln_g, const void* __restrict__ ln_b,
    const void* __restrict__ b1, const void* __restrict__ b2,
    const void* __restrict__ A2, const void* __restrict__ ab1, const void* __restrict__ ab2,
    bf16* __restrict__ W1T, bf16* __restrict__ W2T, bf16* __restrict__ A1T,
    float* __restrict__ prm, float* __restrict__ denom) {
    int b = blockIdx.x, t = threadIdx.x;
    if (b >= ZOFF) {                                // zero denom + pooled (contiguous)
        float4 z4 = {0.f, 0.f, 0.f, 0.f};
        ((float4*)denom)[(b - ZOFF) * 256 + t] = z4;
        return;
    }
    bool isb = probe_bf16(nodes, t);
    if (b < 352) {              // W1T [256][352] = gamma'(k) * W1[k][n], coalesced writes
        int o = b * 256 + t;
        int n = o / XD, k = o - n * XD;
        float g = (k < FIN) ? ldf(ln_g, k, isb) : 1.0f;
        W1T[o] = (bf16)(ldf(W1, k * H1D + n, isb) * g);
    } else if (b < 416) {       // W2T [64][256] = W2[k][n]
        int o = (b - 352) * 256 + t;
        int n = o >> 8, k = o & 255;
        W2T[o] = (bf16)ldf(W2, k * OUTD + n, isb);
    } else if (b < 504) {       // A1T [64][352] = gamma'(k) * A1[k][n]
        int o = (b - 416) * 256 + t;
        int n = o / XD, k = o - n * XD;
        float g = (k < FIN) ? ldf(ln_g, k, isb) : 1.0f;
        A1T[o] = (bf16)(ldf(A1, k * AHD + n, isb) * g);
    } else if (b == 504) {      // b1' = b1 + beta^T W1
        float acc = ldf(b1, t, isb);
        #pragma unroll 4
        for (int k = 0; k < FIN; k++) acc += ldf(ln_b, k, isb) * ldf(W1, k * H1D + t, isb);
        prm[PRM_B1 + t] = acc;
    } else if (b == 505) {      // ab1' = ab1 + beta^T A1
        if (t < AHD) {
            float acc = ldf(ab1, t, isb);
            #pragma unroll 4
            for (int k = 0; k < FIN; k++) acc += ldf(ln_b, k, isb) * ldf(A1, k * AHD + t, isb);
            prm[PRM_AB1 + t] = acc;
        }
    } else {                    // small copies
        if (t < 64)        prm[PRM_B2 + t] = ldf(b2, t, isb);
        else if (t < 320)  prm[PRM_A2 + t - 64] = ldf(A2, t - 64, isb);
        else if (t < 324)  prm[PRM_AB2 + t - 320] = ldf(ab2, t - 320, isb);
    }
}

// ---------------- K1: fused per-edge-tile kernel ----------------
__global__ __launch_bounds__(256, 4) void k_edge(
    const void* __restrict__ nodes, const void* __restrict__ edges0,
    const void* __restrict__ globs, const float* __restrict__ prm,
    const int* __restrict__ bidx, const int* __restrict__ sidx,
    const int* __restrict__ ridx,
    const bf16* __restrict__ W1T, const bf16* __restrict__ W2T,
    const bf16* __restrict__ A1T,
    void* __restrict__ outNE, float* __restrict__ denom,
    float* __restrict__ pooled) {

    __shared__ __align__(16) char smem[SMEM_TOT];
    bf16*  sX    = (bf16*)(smem + SMEM_SX);
    bf16*  sH    = (bf16*)(smem + SMEM_SX);     // overlay after GEMM1 barrier
    bf16*  sA    = (bf16*)(smem + SMEM_SA);     // overlay of sX mid-region
    float* sA2T  = (float*)(smem + SMEM_A2T);
    int*   sSeg  = (int*)(smem + SMEM_SEG);

    const int t  = threadIdx.x;
    const int e0 = blockIdx.x * TE;
    const int ne = min(TE, E_TOT - e0);          // tail block: 16
    const bool isb = probe_bf16(nodes, t);

    const int w = t >> 6, lane = t & 63, quad = lane >> 4, l15 = lane & 15;

    // GEMM1 B-frag prefetch (kk=0): global loads independent of LDS; they cannot
    // sink past __syncthreads, so they issue under phase 1's gather latency.
    const bf16* pW = W1T + (size_t)(w * 64 + l15) * XD + quad * 8;
    const bf16* pA = A1T + (size_t)(w * 16 + l15) * XD + quad * 8;
    bf16x8 bw[4], ba;
    #pragma unroll
    for (int i = 0; i < 4; i++) bw[i] = *(const bf16x8*)(pW + (size_t)i * 16 * XD);
    ba = *(const bf16x8*)pA;

    // Stage A2 transposed [h][k], pre-scaled by 1/sqrt(OUT)=0.125
    { int h = t >> 6, k = t & 63; sA2T[h * 64 + k] = prm[PRM_A2 + k * 4 + h] * 0.125f; }

    // Phase 1: merged gather + folded-LN (8 threads per edge). gamma/beta are in
    // the weights, so the epilogue is just (v - mean) * rstd.
    {
        const int eh = t >> 3, gl = t & 7;
        for (int half = 0; half < 2; half++) {
            const int e = half * 32 + eh;
            if (e >= TE) break;
            if (e >= ne) {               // tail: zero-fill so GEMMs stay finite
                bf16x8 zz = {};
                #pragma unroll
                for (int j = 0; j < 6; j++) {
                    int c = gl + j * 8;
                    if (c < 44) *(bf16x8*)&sX[e * SX_STR + c * 8] = zz;
                }
                continue;
            }
            const int ge = e0 + e;
            const int bi = bidx[ge], si = sidx[ge], ri = ridx[ge];
            if (gl == 0) sSeg[e] = bi * NNODE + ri;
            float v[40];
            #pragma unroll
            for (int j = 0; j < 5; j++) {
                const int c = gl + j * 8;
                const void* base; size_t off;
                if (c < 8)       { base = edges0; off = (size_t)ge * EDIM + c * 8; }
                else if (c < 24) { base = nodes;  off = (size_t)(bi * NNODE + si) * NDIM + (c - 8) * 8; }
                else             { base = nodes;  off = (size_t)(bi * NNODE + ri) * NDIM + (c - 24) * 8; }
                if (isb) {
                    bf16x8 x = *(const bf16x8*)((const bf16*)base + off);
                    #pragma unroll
                    for (int ii = 0; ii < 8; ii++) v[j * 8 + ii] = (float)x[ii];
                } else {
                    const float* sf = (const float*)base + off;
                    float4 f0 = ((const float4*)sf)[0];
                    float4 f1 = ((const float4*)sf)[1];
                    v[j*8+0]=f0.x; v[j*8+1]=f0.y; v[j*8+2]=f0.z; v[j*8+3]=f0.w;
                    v[j*8+4]=f1.x; v[j*8+5]=f1.y; v[j*8+6]=f1.z; v[j*8+7]=f1.w;
                }
            }
            float s = 0.f, sq = 0.f;
            #pragma unroll
            for (int ii = 0; ii < 40; ii++) { s += v[ii]; sq += v[ii] * v[ii]; }
            #pragma unroll
            for (int m = 1; m < 8; m <<= 1) { s += __shfl_xor(s, m); sq += __shfl_xor(sq, m); }
            float mean = s * (1.0f / FIN);
            float var  = sq * (1.0f / FIN) - mean * mean;
            float rstd = rsqrtf(var + 1e-5f);
            #pragma unroll
            for (int j = 0; j < 5; j++) {
                const int c = gl + j * 8;
                bf16x8 o;
                #pragma unroll
                for (int ii = 0; ii < 8; ii++)
                    o[ii] = (bf16)((v[j * 8 + ii] - mean) * rstd);
                *(bf16x8*)&sX[e * SX_STR + c * 8] = o;
            }
            if (gl < 4) {   // globs chunk c = 40+gl (not LayerNormed)
                const int c = 40 + gl;
                size_t off = (size_t)bi * GDIM + gl * 8;
                bf16x8 o;
                if (isb) {
                    o = *(const bf16x8*)((const bf16*)globs + off);
                } else {
                    const float* sf = (const float*)globs + off;
                    float4 f0 = ((const float4*)sf)[0];
                    float4 f1 = ((const float4*)sf)[1];
                    o[0]=(bf16)f0.x; o[1]=(bf16)f0.y; o[2]=(bf16)f0.z; o[3]=(bf16)f0.w;
                    o[4]=(bf16)f1.x; o[5]=(bf16)f1.y; o[6]=(bf16)f1.z; o[7]=(bf16)f1.w;
                }
                *(bf16x8*)&sX[e * SX_STR + c * 8] = o;
            }
        }
    }
    __syncthreads();

    f32x4 z = {0.f, 0.f, 0.f, 0.f};

    // Phase 2: GEMM1 X(48x352)@W1T(->256) + X@A1T(->64), B-frags double-buffered
    f32x4 acc[3][4], accA[3];
    #pragma unroll
    for (int s2 = 0; s2 < 3; s2++) { accA[s2] = z; for (int i = 0; i < 4; i++) acc[s2][i] = z; }
    {
        for (int kk = 0; kk < 11; kk++) {
            bf16x8 bwn[4], ban;
            if (kk < 10) {
                #pragma unroll
                for (int i = 0; i < 4; i++) bwn[i] = *(const bf16x8*)(pW + (size_t)i * 16 * XD + (kk + 1) * 32);
                ban = *(const bf16x8*)(pA + (kk + 1) * 32);
            }
            const int kc = kk * 32 + quad * 8;
            bf16x8 a[3];
            #pragma unroll
            for (int s2 = 0; s2 < 3; s2++) a[s2] = *(bf16x8*)&sX[(s2 * 16 + l15) * SX_STR + kc];
            __builtin_amdgcn_s_setprio(1);
            #pragma unroll
            for (int i = 0; i < 4; i++)
                #pragma unroll
                for (int s2 = 0; s2 < 3; s2++)
                    acc[s2][i] = __builtin_amdgcn_mfma_f32_16x16x32_bf16(a[s2], bw[i], acc[s2][i], 0, 0, 0);
            #pragma unroll
            for (int s2 = 0; s2 < 3; s2++)
                accA[s2] = __builtin_amdgcn_mfma_f32_16x16x32_bf16(a[s2], ba, accA[s2], 0, 0, 0);
            __builtin_amdgcn_s_setprio(0);
            if (kk < 10) {
                #pragma unroll
                for (int i = 0; i < 4; i++) bw[i] = bwn[i];
                ba = ban;
            }
        }
    }
    __syncthreads();   // all sX reads done before overlay writes

    // Phase 3: epilogue -> sH (overlay) and sA (overlay); b1'/ab1' are the folded biases
    #pragma unroll
    for (int i = 0; i < 4; i++) {
        const int n = w * 64 + i * 16 + l15;
        const float bb = prm[PRM_B1 + n];
        #pragma unroll
        for (int s2 = 0; s2 < 3; s2++)
            #pragma unroll
            for (int r = 0; r < 4; r++)
                sH[(s2 * 16 + quad * 4 + r) * SH_STR + n] = (bf16)siluf(acc[s2][i][r] + bb);
    }
    {
        const int n = w * 16 + l15;
        const float ba1 = prm[PRM_AB1 + n];
        #pragma unroll
        for (int s2 = 0; s2 < 3; s2++)
            #pragma unroll
            for (int r = 0; r < 4; r++)
                sA[(s2 * 16 + quad * 4 + r) * SA_STR + n] = (bf16)siluf(accA[s2][r] + ba1);
    }
    // GEMM2 first B-frag prefetch: issues before the barrier, hides under it
    const int n2 = w * 16 + l15;
    const bf16* pW2 = W2T + (size_t)n2 * H1D + quad * 8;
    bf16x8 b2f = *(const bf16x8*)pW2;
    __syncthreads();

    // Phase 4+5 merged: each wave computes its own head's scores from sA (no LDS
    // score buffer, no extra barrier); denom atomics fire immediately and drain
    // under GEMM2.
    float score;
    {
        const int eSc = (lane < TE) ? lane : 0;   // clamp lanes 48..63 in-bounds
        float dot = 0.f;
        #pragma unroll
        for (int c = 0; c < 8; c++) {
            bf16x8 vv = *(bf16x8*)&sA[eSc * SA_STR + c * 8];
            float4 wa = ((float4*)&sA2T[w * 64 + c * 8])[0];
            float4 wb = ((float4*)&sA2T[w * 64 + c * 8])[1];
            dot += (float)vv[0]*wa.x + (float)vv[1]*wa.y + (float)vv[2]*wa.z + (float)vv[3]*wa.w
                 + (float)vv[4]*wb.x + (float)vv[5]*wb.y + (float)vv[6]*wb.z + (float)vv[7]*wb.w;
        }
        score = __expf(dot + prm[PRM_AB2 + w] * 0.125f);   // no max-sub: |logit| << 1
        if (lane < ne) atomicAdd(&denom[sSeg[lane] * NHEADS + w], score);
    }

    // edges0 + per-row scores prefetched into regs; hide under the MFMA loop
    float ev[3][4], sc[3][4];
    #pragma unroll
    for (int s2 = 0; s2 < 3; s2++)
        #pragma unroll
        for (int r = 0; r < 4; r++) {
            const int row = s2 * 16 + quad * 4 + r;
            sc[s2][r] = __shfl(score, row);
            if (row < ne) {
                size_t off = (size_t)(e0 + row) * EDIM + n2;
                ev[s2][r] = isb ? (float)((const bf16*)edges0)[off] : ((const float*)edges0)[off];
            } else ev[s2][r] = 0.f;
        }

    // GEMM2 H(48x256)@W2T(->64), B-frags double-buffered
    f32x4 c2[3] = {z, z, z};
    for (int kk = 0; kk < 8; kk++) {
        bf16x8 b2n;
        if (kk < 7) b2n = *(const bf16x8*)(pW2 + (kk + 1) * 32);
        const int kc = kk * 32 + quad * 8;
        bf16x8 a0 = *(bf16x8*)&sH[l15 * SH_STR + kc];
        bf16x8 a1 = *(bf16x8*)&sH[(16 + l15) * SH_STR + kc];
        bf16x8 a2 = *(bf16x8*)&sH[(32 + l15) * SH_STR + kc];
        __builtin_amdgcn_s_setprio(1);
        c2[0] = __builtin_amdgcn_mfma_f32_16x16x32_bf16(a0, b2f, c2[0], 0, 0, 0);
        c2[1] = __builtin_amdgcn_mfma_f32_16x16x32_bf16(a1, b2f, c2[1], 0, 0, 0);
        c2[2] = __builtin_amdgcn_mfma_f32_16x16x32_bf16(a2, b2f, c2[2], 0, 0, 0);
        __builtin_amdgcn_s_setprio(0);
        if (kk < 7) b2f = b2n;
    }
    const float bb2 = prm[PRM_B2 + n2];
    #pragma unroll
    for (int s2 = 0; s2 < 3; s2++)
        #pragma unroll
        for (int r = 0; r < 4; r++) {
            const int row = s2 * 16 + quad * 4 + r;
            if (row < ne) {
                size_t off = (size_t)(e0 + row) * EDIM + n2;
                float v = c2[s2][r] + bb2 + ev[s2][r];
                if (isb) ((bf16*)outNE)[off] = (bf16)v;
                else     ((float*)outNE)[off] = v;
                atomicAdd(&pooled[(size_t)sSeg[row] * OUTD + n2], v * sc[s2][r]);
            }
        }
}

// ---------------- K_norm: pooled / denom -> d_out ----------------
__global__ __launch_bounds__(256) void k_norm(const float* __restrict__ pooled,
                                              const float* __restrict__ denom,
                                              const void* __restrict__ nodes,
                                              void* __restrict__ d_out) {
    int i = blockIdx.x * 256 + threadIdx.x;   // NSEG*OUTD = 262144
    bool isb = probe_bf16(nodes, threadIdx.x);
    int s = i >> 6, j = i & 63, h = j >> 4;
    float den = denom[s * 4 + h];
    float v = (den > 0.f) ? pooled[i] / den : 0.0f;
    size_t po = (size_t)E_TOT * OUTD + i;
    if (isb) ((bf16*)d_out)[po] = (bf16)v;
    else     ((float*)d_out)[po] = v;
}

static char* align_up(char* p, size_t a) {
    return (char*)(((uintptr_t)p + (a - 1)) & ~(uintptr_t)(a - 1));
}

extern "C" void kernel_launch(void* const* d_in, const int* in_sizes, int n_in,
                              void* d_out, int out_size, void* d_ws, size_t ws_size,
                              hipStream_t stream) {
    const void* nodes  = d_in[0];
    const void* edges0 = d_in[1];
    const void* globs  = d_in[2];
    const void* ln_g   = d_in[3];
    const void* ln_b   = d_in[4];
    const void* W1     = d_in[5];
    const void* b1     = d_in[6];
    const void* W2     = d_in[7];
    const void* b2     = d_in[8];
    const void* A1     = d_in[9];
    const void* ab1    = d_in[10];
    const void* A2     = d_in[11];
    const void* ab2    = d_in[12];
    const int*  bidx   = (const int*)d_in[13];
    const int*  sidx   = (const int*)d_in[14];
    const int*  ridx   = (const int*)d_in[15];

    char* p = (char*)d_ws;
    float*    prm    = (float*)p;    p = align_up(p + PRM_TOT * 4, 256);
    bf16*     W1T    = (bf16*)p;     p = align_up(p + XD * H1D * 2, 256);
    bf16*     W2T    = (bf16*)p;     p = align_up(p + H1D * OUTD * 2, 256);
    bf16*     A1T    = (bf16*)p;     p = align_up(p + XD * AHD * 2, 256);
    float*    denom  = (float*)p;    p += NSEG * NHEADS * 4;         // 64 KB
    float*    pooled = (float*)p;    p += (size_t)NSEG * OUTD * 4;   // 1 MB (contiguous w/ denom)

    k_prep<<<dim3(ZOFF + ZBLK), dim3(256), 0, stream>>>(
        nodes, W1, W2, A1, ln_g, ln_b, b1, b2, A2, ab1, ab2,
        W1T, W2T, A1T, prm, denom);
    k_edge<<<dim3((E_TOT + TE - 1) / TE), dim3(256), 0, stream>>>(
        nodes, edges0, globs, prm,
        bidx, sidx, ridx, W1T, W2T, A1T, d_out, denom, pooled);
    k_norm<<<dim3(NSEG * OUTD / 256), dim3(256), 0, stream>>>(pooled, denom, nodes, d_out);
}

// Round 3
// 395.378 us; speedup vs baseline: 1.0651x; 1.0651x over previous
//
#include <hip/hip_runtime.h>
#include <hip/hip_bf16.h>
#include <cstdint>

typedef __bf16 bf16;
typedef __bf16 bf16x8 __attribute__((ext_vector_type(8)));
typedef float f32x4 __attribute__((ext_vector_type(4)));

#define E_TOT   262144
#define NNODE   512
#define NDIM    128
#define EDIM    64
#define GDIM    32
#define FIN     320
#define XD      352   // FIN + CTX(32)
#define H1D     256
#define OUTD    64
#define AHD     64
#define NHEADS  4
#define NSEG    4096
#define TE      48    // edges per block (4 blocks/CU)

#define SX_STR  360   // 720B = 180 words, %32=20 -> 2-way alias (free)
#define SH_STR  264   // 528B = 132 words, %32=4  -> 2-way
#define SA_STR  72    // 144B = 36 words,  %32=4  -> 2-way

// fp32 params block (floats). LN gamma/beta folded into weights in k_prep:
// W1T,A1T pre-scaled by gamma; b1' = b1 + beta^T W1 ; ab1' = ab1 + beta^T A1.
#define PRM_B1  0     // 256
#define PRM_B2  256   // 64
#define PRM_A2  320   // 256 (raw A2, row-major [64][4])
#define PRM_AB1 576   // 64
#define PRM_AB2 640   // 4
#define PRM_TOT 644

// LDS layout (bytes). sX 48x360x2=34560; sH (48x264x2=25344) overlays sX head;
// sA (48x72x2=6912) overlays sX at 25600 (ends 32512, inside 34560).
#define SMEM_SX    0
#define SMEM_SA    25600
#define SMEM_SCORE 34560   // float[48*4] = 768
#define SMEM_A2    35328   // float[256]  = 1024
#define SMEM_IDX   36352   // 4 x int[48] = 768
#define SMEM_TOT   37120   // x4 = 148480 <= 160K -> 4 blocks/CU

#define ZOFF 507           // k_prep blocks >= ZOFF zero denom+pooled
#define ZBLK 272           // 272 * 256 * 16B = 1114112B = denom(64K) + pooled(1M)

__device__ __forceinline__ float siluf(float v) {
    return v / (1.0f + __expf(-v));
}

__device__ __forceinline__ float ldf(const void* p, int i, bool isb) {
    return isb ? (float)((const bf16*)p)[i] : ((const float*)p)[i];
}

// Per-wave dtype probe: 1=bf16 data, 0=fp32 data. Reads first 256 u16 of nodes.
__device__ __forceinline__ bool probe_bf16(const void* nodes, int t) {
    const unsigned short* u16 = (const unsigned short*)nodes;
    int lane = t & 63;
    int pl = 0;
    #pragma unroll
    for (int i = 0; i < 4; i++) {
        unsigned short u = u16[lane * 4 + i];
        int expo = (u >> 7) & 0xFF;
        pl += (((u & 0x7FFF) == 0) || (expo >= 97 && expo <= 137)) ? 1 : 0;
    }
    #pragma unroll
    for (int m = 1; m < 64; m <<= 1) pl += __shfl_xor(pl, m);
    return pl >= 240;
}

// ---------------- K_prep: gamma-folded transpose + bias fold + zero-fill ----------------
// Transposes keep R0's input-linear order: coalesced reads, scattered writes.
__global__ __launch_bounds__(256) void k_prep(
    const void* __restrict__ nodes,
    const void* __restrict__ W1, const void* __restrict__ W2, const void* __restrict__ A1,
    const void* __restrict__ ln_g, const void* __restrict__ ln_b,
    const void* __restrict__ b1, const void* __restrict__ b2,
    const void* __restrict__ A2, const void* __restrict__ ab1, const void* __restrict__ ab2,
    bf16* __restrict__ W1T, bf16* __restrict__ W2T, bf16* __restrict__ A1T,
    float* __restrict__ prm, float* __restrict__ denom) {
    int b = blockIdx.x, t = threadIdx.x;
    if (b >= ZOFF) {                                // zero denom + pooled (contiguous)
        float4 z4 = {0.f, 0.f, 0.f, 0.f};
        ((float4*)denom)[(b - ZOFF) * 256 + t] = z4;
        return;
    }
    bool isb = probe_bf16(nodes, t);
    if (b < 352) {              // W1 row k=b: W1T[n][k] = gamma'(k)*W1[k][n]
        int k = b, n = t;
        float g = (k < FIN) ? ldf(ln_g, k, isb) : 1.0f;
        W1T[n * XD + k] = (bf16)(ldf(W1, k * H1D + n, isb) * g);
    } else if (b < 416) {       // W2 [256][64] -> W2T [64][256]
        int i = (b - 352) * 256 + t;
        int k = i >> 6, n = i & 63;
        W2T[n * H1D + k] = (bf16)ldf(W2, i, isb);
    } else if (b < 504) {       // A1 [352][64] -> A1T [64][352], gamma-folded
        int i = (b - 416) * 256 + t;
        int k = i >> 6, n = i & 63;
        float g = (k < FIN) ? ldf(ln_g, k, isb) : 1.0f;
        A1T[n * XD + k] = (bf16)(ldf(A1, i, isb) * g);
    } else if (b == 504) {      // b1' = b1 + beta^T W1  (coalesced over t)
        float acc = ldf(b1, t, isb);
        #pragma unroll 4
        for (int k = 0; k < FIN; k++) acc += ldf(ln_b, k, isb) * ldf(W1, k * H1D + t, isb);
        prm[PRM_B1 + t] = acc;
    } else if (b == 505) {      // ab1' = ab1 + beta^T A1
        if (t < AHD) {
            float acc = ldf(ab1, t, isb);
            #pragma unroll 4
            for (int k = 0; k < FIN; k++) acc += ldf(ln_b, k, isb) * ldf(A1, k * AHD + t, isb);
            prm[PRM_AB1 + t] = acc;
        }
    } else {                    // small copies
        prm[PRM_A2 + t] = ldf(A2, t, isb);
        if (t < 64) prm[PRM_B2 + t] = ldf(b2, t, isb);
        if (t < 4)  prm[PRM_AB2 + t] = ldf(ab2, t, isb);
    }
}

// ---------------- K1: fused per-edge-tile kernel (R0 structure + LN fold) ----------------
__global__ __launch_bounds__(256, 4) void k_edge(
    const void* __restrict__ nodes, const void* __restrict__ edges0,
    const void* __restrict__ globs, const float* __restrict__ prm,
    const int* __restrict__ bidx, const int* __restrict__ sidx,
    const int* __restrict__ ridx,
    const bf16* __restrict__ W1T, const bf16* __restrict__ W2T,
    const bf16* __restrict__ A1T,
    void* __restrict__ outNE, float* __restrict__ denom,
    float* __restrict__ pooled) {

    __shared__ __align__(16) char smem[SMEM_TOT];
    bf16*  sX    = (bf16*)(smem + SMEM_SX);
    bf16*  sH    = (bf16*)(smem + SMEM_SX);     // overlay after GEMM1 barrier
    bf16*  sA    = (bf16*)(smem + SMEM_SA);     // overlay of sX mid-region
    float* sScore= (float*)(smem + SMEM_SCORE); // [48][4] exp-scores
    float* sA2   = (float*)(smem + SMEM_A2);
    int*   sBi   = (int*)(smem + SMEM_IDX);
    int*   sSi   = sBi + TE;
    int*   sRi   = sBi + 2 * TE;
    int*   sSeg  = sBi + 3 * TE;

    const int t  = threadIdx.x;
    const int e0 = blockIdx.x * TE;
    const int ne = min(TE, E_TOT - e0);          // tail block: 16
    const bool isb = probe_bf16(nodes, t);

    // Phase 0: stage indices + A2 weights
    if (t < TE) {
        int ge = e0 + t;
        if (t < ne) {
            int bi = bidx[ge], si = sidx[ge], ri = ridx[ge];
            sBi[t] = bi; sSi[t] = si; sRi[t] = ri;
            sSeg[t] = bi * NNODE + ri;
        } else {
            sBi[t] = 0; sSi[t] = 0; sRi[t] = 0; sSeg[t] = 0;
        }
    } else if (t >= 64 && t < 128) {
        ((float4*)sA2)[t - 64] = ((const float4*)(prm + PRM_A2))[t - 64];
    }
    __syncthreads();

    // Phase 1: merged gather + folded-LN in registers (8 threads per edge).
    // gamma/beta live in the weights, so the epilogue is just (v - mean)*rstd.
    {
        const int eh = t >> 3, gl = t & 7;
        for (int half = 0; half < 2; half++) {
            const int e = half * 32 + eh;
            if (e >= TE) break;
            if (e >= ne) {               // tail: zero-fill so GEMMs stay finite
                bf16x8 zz = {};
                #pragma unroll
                for (int j = 0; j < 6; j++) {
                    int c = gl + j * 8;
                    if (c < 44) *(bf16x8*)&sX[e * SX_STR + c * 8] = zz;
                }
                continue;
            }
            const int ge = e0 + e;
            const int bi = sBi[e], si = sSi[e], ri = sRi[e];
            float v[40];
            #pragma unroll
            for (int j = 0; j < 5; j++) {
                const int c = gl + j * 8;
                const void* base; size_t off;
                if (c < 8)       { base = edges0; off = (size_t)ge * EDIM + c * 8; }
                else if (c < 24) { base = nodes;  off = (size_t)(bi * NNODE + si) * NDIM + (c - 8) * 8; }
                else             { base = nodes;  off = (size_t)(bi * NNODE + ri) * NDIM + (c - 24) * 8; }
                if (isb) {
                    bf16x8 x = *(const bf16x8*)((const bf16*)base + off);
                    #pragma unroll
                    for (int ii = 0; ii < 8; ii++) v[j * 8 + ii] = (float)x[ii];
                } else {
                    const float* sf = (const float*)base + off;
                    float4 f0 = ((const float4*)sf)[0];
                    float4 f1 = ((const float4*)sf)[1];
                    v[j*8+0]=f0.x; v[j*8+1]=f0.y; v[j*8+2]=f0.z; v[j*8+3]=f0.w;
                    v[j*8+4]=f1.x; v[j*8+5]=f1.y; v[j*8+6]=f1.z; v[j*8+7]=f1.w;
                }
            }
            float s = 0.f, sq = 0.f;
            #pragma unroll
            for (int ii = 0; ii < 40; ii++) { s += v[ii]; sq += v[ii] * v[ii]; }
            #pragma unroll
            for (int m = 1; m < 8; m <<= 1) { s += __shfl_xor(s, m); sq += __shfl_xor(sq, m); }
            float mean = s * (1.0f / FIN);
            float var  = sq * (1.0f / FIN) - mean * mean;
            float rstd = rsqrtf(var + 1e-5f);
            #pragma unroll
            for (int j = 0; j < 5; j++) {
                const int c = gl + j * 8;
                bf16x8 o;
                #pragma unroll
                for (int ii = 0; ii < 8; ii++)
                    o[ii] = (bf16)((v[j * 8 + ii] - mean) * rstd);
                *(bf16x8*)&sX[e * SX_STR + c * 8] = o;
            }
            if (gl < 4) {   // globs chunk c = 40+gl (not LayerNormed)
                const int c = 40 + gl;
                size_t off = (size_t)bi * GDIM + gl * 8;
                bf16x8 o;
                if (isb) {
                    o = *(const bf16x8*)((const bf16*)globs + off);
                } else {
                    const float* sf = (const float*)globs + off;
                    float4 f0 = ((const float4*)sf)[0];
                    float4 f1 = ((const float4*)sf)[1];
                    o[0]=(bf16)f0.x; o[1]=(bf16)f0.y; o[2]=(bf16)f0.z; o[3]=(bf16)f0.w;
                    o[4]=(bf16)f1.x; o[5]=(bf16)f1.y; o[6]=(bf16)f1.z; o[7]=(bf16)f1.w;
                }
                *(bf16x8*)&sX[e * SX_STR + c * 8] = o;
            }
        }
    }
    __syncthreads();

    const int w = t >> 6, lane = t & 63, quad = lane >> 4, l15 = lane & 15;
    f32x4 z = {0.f, 0.f, 0.f, 0.f};

    // Phase 2: GEMM1 X(48x352)@W1T(->256) + X@A1T(->64), B-frags double-buffered
    f32x4 acc[3][4], accA[3];
    #pragma unroll
    for (int s2 = 0; s2 < 3; s2++) { accA[s2] = z; for (int i = 0; i < 4; i++) acc[s2][i] = z; }
    {
        const bf16* pW = W1T + (size_t)(w * 64 + l15) * XD + quad * 8;
        const bf16* pA = A1T + (size_t)(w * 16 + l15) * XD + quad * 8;
        bf16x8 bw[4], ba;
        #pragma unroll
        for (int i = 0; i < 4; i++) bw[i] = *(const bf16x8*)(pW + (size_t)i * 16 * XD);
        ba = *(const bf16x8*)pA;
        for (int kk = 0; kk < 11; kk++) {
            bf16x8 bwn[4], ban;
            if (kk < 10) {
                #pragma unroll
                for (int i = 0; i < 4; i++) bwn[i] = *(const bf16x8*)(pW + (size_t)i * 16 * XD + (kk + 1) * 32);
                ban = *(const bf16x8*)(pA + (kk + 1) * 32);
            }
            const int kc = kk * 32 + quad * 8;
            bf16x8 a[3];
            #pragma unroll
            for (int s2 = 0; s2 < 3; s2++) a[s2] = *(bf16x8*)&sX[(s2 * 16 + l15) * SX_STR + kc];
            #pragma unroll
            for (int i = 0; i < 4; i++)
                #pragma unroll
                for (int s2 = 0; s2 < 3; s2++)
                    acc[s2][i] = __builtin_amdgcn_mfma_f32_16x16x32_bf16(a[s2], bw[i], acc[s2][i], 0, 0, 0);
            #pragma unroll
            for (int s2 = 0; s2 < 3; s2++)
                accA[s2] = __builtin_amdgcn_mfma_f32_16x16x32_bf16(a[s2], ba, accA[s2], 0, 0, 0);
            if (kk < 10) {
                #pragma unroll
                for (int i = 0; i < 4; i++) bw[i] = bwn[i];
                ba = ban;
            }
        }
    }
    __syncthreads();   // all sX reads done before overlay writes

    // Phase 3: epilogue -> sH (overlay) and sA (overlay); b1'/ab1' folded biases
    #pragma unroll
    for (int i = 0; i < 4; i++) {
        const int n = w * 64 + i * 16 + l15;
        const float bb = prm[PRM_B1 + n];
        #pragma unroll
        for (int s2 = 0; s2 < 3; s2++)
            #pragma unroll
            for (int r = 0; r < 4; r++)
                sH[(s2 * 16 + quad * 4 + r) * SH_STR + n] = (bf16)siluf(acc[s2][i][r] + bb);
    }
    {
        const int n = w * 16 + l15;
        const float ba1 = prm[PRM_AB1 + n];
        #pragma unroll
        for (int s2 = 0; s2 < 3; s2++)
            #pragma unroll
            for (int r = 0; r < 4; r++)
                sA[(s2 * 16 + quad * 4 + r) * SA_STR + n] = (bf16)siluf(accA[s2][r] + ba1);
    }
    __syncthreads();

    // Phase 4: scores = exp((silu(X@A1)@A2 + ab2)/8)  (no max-sub: |logit| << 1)
    if (t < TE * NHEADS) {
        const int e = t >> 2, h = t & 3;
        if (e < ne) {
            float dot = 0.f;
            #pragma unroll
            for (int c = 0; c < 8; c++) {
                bf16x8 vv = *(bf16x8*)&sA[e * SA_STR + c * 8];
                #pragma unroll
                for (int ii = 0; ii < 8; ii++)
                    dot += (float)vv[ii] * sA2[(c * 8 + ii) * NHEADS + h];
            }
            float ex = __expf((dot + prm[PRM_AB2 + h]) * 0.125f);
            sScore[e * 4 + h] = ex;
            atomicAdd(&denom[sSeg[e] * NHEADS + h], ex);
        }
    }
    __syncthreads();

    // Phase 5: GEMM2 H@W2T + b2 + edges0 -> new_edges; fused pooled atomics
    {
        f32x4 c2[3] = {z, z, z};
        const int n = w * 16 + l15;          // head = w
        const bf16* pW2 = W2T + (size_t)n * H1D + quad * 8;
        bf16x8 b2f = *(const bf16x8*)pW2;
        for (int kk = 0; kk < 8; kk++) {
            bf16x8 b2n;
            if (kk < 7) b2n = *(const bf16x8*)(pW2 + (kk + 1) * 32);
            const int kc = kk * 32 + quad * 8;
            #pragma unroll
            for (int s2 = 0; s2 < 3; s2++) {
                bf16x8 a = *(bf16x8*)&sH[(s2 * 16 + l15) * SH_STR + kc];
                c2[s2] = __builtin_amdgcn_mfma_f32_16x16x32_bf16(a, b2f, c2[s2], 0, 0, 0);
            }
            if (kk < 7) b2f = b2n;
        }
        const float bb2 = prm[PRM_B2 + n];
        #pragma unroll
        for (int s2 = 0; s2 < 3; s2++)
            #pragma unroll
            for (int r = 0; r < 4; r++) {
                const int row = s2 * 16 + quad * 4 + r;
                if (row < ne) {
                    size_t off = (size_t)(e0 + row) * EDIM + n;
                    float ev = isb ? (float)((const bf16*)edges0)[off] : ((const float*)edges0)[off];
                    float v = c2[s2][r] + bb2 + ev;
                    // non-temporal: new_edges is write-once, never re-read ->
                    // keep the 33.5 MB stream from evicting hot weights/nodes in L2
                    if (isb) { bf16 bv = (bf16)v; __builtin_nontemporal_store(bv, &((bf16*)outNE)[off]); }
                    else     { __builtin_nontemporal_store(v, &((float*)outNE)[off]); }
                    float ex = sScore[row * 4 + w];
                    atomicAdd(&pooled[(size_t)sSeg[row] * OUTD + n], v * ex);
                }
            }
    }
}

// ---------------- K_norm: pooled / denom -> d_out ----------------
__global__ __launch_bounds__(256) void k_norm(const float* __restrict__ pooled,
                                              const float* __restrict__ denom,
                                              const void* __restrict__ nodes,
                                              void* __restrict__ d_out) {
    int i = blockIdx.x * 256 + threadIdx.x;   // NSEG*OUTD = 262144
    bool isb = probe_bf16(nodes, threadIdx.x);
    int s = i >> 6, j = i & 63, h = j >> 4;
    float den = denom[s * 4 + h];
    float v = (den > 0.f) ? pooled[i] / den : 0.0f;
    size_t po = (size_t)E_TOT * OUTD + i;
    if (isb) ((bf16*)d_out)[po] = (bf16)v;
    else     ((float*)d_out)[po] = v;
}

static char* align_up(char* p, size_t a) {
    return (char*)(((uintptr_t)p + (a - 1)) & ~(uintptr_t)(a - 1));
}

extern "C" void kernel_launch(void* const* d_in, const int* in_sizes, int n_in,
                              void* d_out, int out_size, void* d_ws, size_t ws_size,
                              hipStream_t stream) {
    const void* nodes  = d_in[0];
    const void* edges0 = d_in[1];
    const void* globs  = d_in[2];
    const void* ln_g   = d_in[3];
    const void* ln_b   = d_in[4];
    const void* W1     = d_in[5];
    const void* b1     = d_in[6];
    const void* W2     = d_in[7];
    const void* b2     = d_in[8];
    const void* A1     = d_in[9];
    const void* ab1    = d_in[10];
    const void* A2     = d_in[11];
    const void* ab2    = d_in[12];
    const int*  bidx   = (const int*)d_in[13];
    const int*  sidx   = (const int*)d_in[14];
    const int*  ridx   = (const int*)d_in[15];

    char* p = (char*)d_ws;
    float*    prm    = (float*)p;    p = align_up(p + PRM_TOT * 4, 256);
    bf16*     W1T    = (bf16*)p;     p = align_up(p + XD * H1D * 2, 256);
    bf16*     W2T    = (bf16*)p;     p = align_up(p + H1D * OUTD * 2, 256);
    bf16*     A1T    = (bf16*)p;     p = align_up(p + XD * AHD * 2, 256);
    float*    denom  = (float*)p;    p += NSEG * NHEADS * 4;         // 64 KB
    float*    pooled = (float*)p;    p += (size_t)NSEG * OUTD * 4;   // 1 MB (contiguous w/ denom)

    k_prep<<<dim3(ZOFF + ZBLK), dim3(256), 0, stream>>>(
        nodes, W1, W2, A1, ln_g, ln_b, b1, b2, A2, ab1, ab2,
        W1T, W2T, A1T, prm, denom);
    k_edge<<<dim3((E_TOT + TE - 1) / TE), dim3(256), 0, stream>>>(
        nodes, edges0, globs, prm,
        bidx, sidx, ridx, W1T, W2T, A1T, d_out, denom, pooled);
    k_norm<<<dim3(NSEG * OUTD / 256), dim3(256), 0, stream>>>(pooled, denom, nodes, d_out);
}

// Round 4
// 357.697 us; speedup vs baseline: 1.1773x; 1.1053x over previous
//
#include <hip/hip_runtime.h>
#include <hip/hip_bf16.h>
#include <cstdint>

typedef __bf16 bf16;
typedef __bf16 bf16x8 __attribute__((ext_vector_type(8)));
typedef float f32x4 __attribute__((ext_vector_type(4)));

#define E_TOT   262144
#define NNODE   512
#define NDIM    128
#define EDIM    64
#define GDIM    32
#define FIN     320
#define XD      352   // FIN + CTX(32)
#define H1D     256
#define OUTD    64
#define AHD     64
#define NHEADS  4
#define NSEG    4096
#define TE      48    // edges per block (4 blocks/CU)

#define SX_STR  360   // 720B = 180 words, %32=20 -> 2-way alias (free)
#define SH_STR  264   // 528B = 132 words, %32=4  -> 2-way
#define SA_STR  72    // 144B = 36 words,  %32=4  -> 2-way

// fp32 params block layout (floats) -- R0 layout, no weight folding
#define PRM_LNG 0
#define PRM_LNB 320
#define PRM_B1  640
#define PRM_B2  896
#define PRM_A2  960
#define PRM_AB1 1216
#define PRM_AB2 1280
#define PRM_TOT 1284

// LDS layout (bytes). sX 48x360x2=34560; sH (48x264x2=25344) overlays sX head;
// sA (48x72x2=6912) overlays sX at 25600 (ends 32512, inside 34560).
// LN params NOT in LDS (read from L1-hot prm) -> smaller block, no phase-0 barrier.
#define SMEM_SX    0
#define SMEM_SA    25600
#define SMEM_SCORE 34560   // float[48*4] = 768
#define SMEM_A2    35328   // float[256]  = 1024
#define SMEM_SEG   36352   // int[48]     = 192
#define SMEM_TOT   36544   // x4 = 146176 <= 160K -> 4 blocks/CU

#define ZOFF 510           // k_prep blocks >= ZOFF zero denom+pooled
#define ZBLK 272           // 272 * 256 * 16B = 1114112B = denom(64K) + pooled(1M)

__device__ __forceinline__ float siluf(float v) {
    return v / (1.0f + __expf(-v));
}

// Per-wave dtype probe: 1=bf16 data, 0=fp32 data. Reads first 256 u16 of nodes.
__device__ __forceinline__ bool probe_bf16(const void* nodes, int t) {
    const unsigned short* u16 = (const unsigned short*)nodes;
    int lane = t & 63;
    int pl = 0;
    #pragma unroll
    for (int i = 0; i < 4; i++) {
        unsigned short u = u16[lane * 4 + i];
        int expo = (u >> 7) & 0xFF;
        pl += (((u & 0x7FFF) == 0) || (expo >= 97 && expo <= 137)) ? 1 : 0;
    }
    #pragma unroll
    for (int m = 1; m < 64; m <<= 1) pl += __shfl_xor(pl, m);
    return pl >= 240;
}

// ---------------- K_prep: weights transpose + params + zero-fill (R0 + zero) ----------------
__global__ __launch_bounds__(256) void k_prep(
    const void* __restrict__ nodes,
    const void* __restrict__ W1, const void* __restrict__ W2, const void* __restrict__ A1,
    const void* __restrict__ ln_g, const void* __restrict__ ln_b,
    const void* __restrict__ b1, const void* __restrict__ b2,
    const void* __restrict__ A2, const void* __restrict__ ab1, const void* __restrict__ ab2,
    bf16* __restrict__ W1T, bf16* __restrict__ W2T, bf16* __restrict__ A1T,
    float* __restrict__ prm, float* __restrict__ denom) {
    int b = blockIdx.x, t = threadIdx.x;
    if (b >= ZOFF) {                                // zero denom + pooled (contiguous)
        float4 z4 = {0.f, 0.f, 0.f, 0.f};
        ((float4*)denom)[(b - ZOFF) * 256 + t] = z4;
        return;
    }
    bool isb = probe_bf16(nodes, t);
    if (b < 352) {                                  // W1 [352][256] -> W1T [256][352]
        int i = b * 256 + t;
        int k = i / H1D, n = i % H1D;
        float v = isb ? (float)((const bf16*)W1)[i] : ((const float*)W1)[i];
        W1T[n * XD + k] = (bf16)v;
    } else if (b < 416) {                           // W2 [256][64] -> W2T [64][256]
        int i = (b - 352) * 256 + t;
        int k = i / OUTD, n = i % OUTD;
        float v = isb ? (float)((const bf16*)W2)[i] : ((const float*)W2)[i];
        W2T[n * H1D + k] = (bf16)v;
    } else if (b < 504) {                           // A1 [352][64] -> A1T [64][352]
        int i = (b - 416) * 256 + t;
        int k = i / AHD, n = i % AHD;
        float v = isb ? (float)((const bf16*)A1)[i] : ((const float*)A1)[i];
        A1T[n * XD + k] = (bf16)v;
    } else {                                        // params -> fp32 block
        int i = (b - 504) * 256 + t;
        if (i < PRM_TOT) {
            const void* src; int off;
            if (i < 320)       { src = ln_g; off = i; }
            else if (i < 640)  { src = ln_b; off = i - 320; }
            else if (i < 896)  { src = b1;   off = i - 640; }
            else if (i < 960)  { src = b2;   off = i - 896; }
            else if (i < 1216) { src = A2;   off = i - 960; }
            else if (i < 1280) { src = ab1;  off = i - 1216; }
            else               { src = ab2;  off = i - 1280; }
            prm[i] = isb ? (float)((const bf16*)src)[off] : ((const float*)src)[off];
        }
    }
}

// ---------------- K1: fused per-edge-tile kernel (R0 structure, phase 0 removed) ----------------
__global__ __launch_bounds__(256, 4) void k_edge(
    const void* __restrict__ nodes, const void* __restrict__ edges0,
    const void* __restrict__ globs, const float* __restrict__ prm,
    const int* __restrict__ bidx, const int* __restrict__ sidx,
    const int* __restrict__ ridx,
    const bf16* __restrict__ W1T, const bf16* __restrict__ W2T,
    const bf16* __restrict__ A1T,
    void* __restrict__ outNE, float* __restrict__ denom,
    float* __restrict__ pooled) {

    __shared__ __align__(16) char smem[SMEM_TOT];
    bf16*  sX    = (bf16*)(smem + SMEM_SX);
    bf16*  sH    = (bf16*)(smem + SMEM_SX);     // overlay after GEMM1 barrier
    bf16*  sA    = (bf16*)(smem + SMEM_SA);     // overlay of sX mid-region
    float* sScore= (float*)(smem + SMEM_SCORE); // [48][4] exp-scores
    float* sA2   = (float*)(smem + SMEM_A2);
    int*   sSeg  = (int*)(smem + SMEM_SEG);

    const int t  = threadIdx.x;
    const int e0 = blockIdx.x * TE;
    const int ne = min(TE, E_TOT - e0);          // tail block: 16
    const bool isb = probe_bf16(nodes, t);

    // A2 staging (read in phase 4, protected by the post-phase-1 barrier)
    if (t < 64) ((float4*)sA2)[t] = ((const float4*)(prm + PRM_A2))[t];

    // Phase 1: merged gather + LayerNorm in registers (8 threads per edge).
    // No phase 0: each thread loads its edge's indices directly (8 consecutive
    // lanes hit the same address -> one L2 request); sSeg written by lane gl==0.
    // gamma/beta read per-thread from the L1-hot prm block (no LDS staging).
    {
        const int eh = t >> 3, gl = t & 7;
        for (int half = 0; half < 2; half++) {
            const int e = half * 32 + eh;
            if (e >= TE) break;
            if (e >= ne) {               // tail: zero-fill so GEMMs stay finite
                bf16x8 zz = {};
                #pragma unroll
                for (int j = 0; j < 6; j++) {
                    int c = gl + j * 8;
                    if (c < 44) *(bf16x8*)&sX[e * SX_STR + c * 8] = zz;
                }
                continue;
            }
            const int ge = e0 + e;
            const int bi = bidx[ge], si = sidx[ge], ri = ridx[ge];
            if (gl == 0) sSeg[e] = bi * NNODE + ri;
            float v[40];
            #pragma unroll
            for (int j = 0; j < 5; j++) {
                const int c = gl + j * 8;
                const void* base; size_t off;
                if (c < 8)       { base = edges0; off = (size_t)ge * EDIM + c * 8; }
                else if (c < 24) { base = nodes;  off = (size_t)(bi * NNODE + si) * NDIM + (c - 8) * 8; }
                else             { base = nodes;  off = (size_t)(bi * NNODE + ri) * NDIM + (c - 24) * 8; }
                if (isb) {
                    bf16x8 x = *(const bf16x8*)((const bf16*)base + off);
                    #pragma unroll
                    for (int ii = 0; ii < 8; ii++) v[j * 8 + ii] = (float)x[ii];
                } else {
                    const float* sf = (const float*)base + off;
                    float4 f0 = ((const float4*)sf)[0];
                    float4 f1 = ((const float4*)sf)[1];
                    v[j*8+0]=f0.x; v[j*8+1]=f0.y; v[j*8+2]=f0.z; v[j*8+3]=f0.w;
                    v[j*8+4]=f1.x; v[j*8+5]=f1.y; v[j*8+6]=f1.z; v[j*8+7]=f1.w;
                }
            }
            float s = 0.f, sq = 0.f;
            #pragma unroll
            for (int ii = 0; ii < 40; ii++) { s += v[ii]; sq += v[ii] * v[ii]; }
            #pragma unroll
            for (int m = 1; m < 8; m <<= 1) { s += __shfl_xor(s, m); sq += __shfl_xor(sq, m); }
            float mean = s * (1.0f / FIN);
            float var  = sq * (1.0f / FIN) - mean * mean;
            float rstd = rsqrtf(var + 1e-5f);
            #pragma unroll
            for (int j = 0; j < 5; j++) {
                const int c = gl + j * 8;
                float4 g0 = ((const float4*)(prm + PRM_LNG))[c * 2];
                float4 g1 = ((const float4*)(prm + PRM_LNG))[c * 2 + 1];
                float4 p0 = ((const float4*)(prm + PRM_LNB))[c * 2];
                float4 p1 = ((const float4*)(prm + PRM_LNB))[c * 2 + 1];
                float gg[8] = {g0.x, g0.y, g0.z, g0.w, g1.x, g1.y, g1.z, g1.w};
                float pp[8] = {p0.x, p0.y, p0.z, p0.w, p1.x, p1.y, p1.z, p1.w};
                bf16x8 o;
                #pragma unroll
                for (int ii = 0; ii < 8; ii++)
                    o[ii] = (bf16)((v[j * 8 + ii] - mean) * rstd * gg[ii] + pp[ii]);
                *(bf16x8*)&sX[e * SX_STR + c * 8] = o;
            }
            if (gl < 4) {   // globs chunk c = 40+gl (not LayerNormed)
                const int c = 40 + gl;
                size_t off = (size_t)bi * GDIM + gl * 8;
                bf16x8 o;
                if (isb) {
                    o = *(const bf16x8*)((const bf16*)globs + off);
                } else {
                    const float* sf = (const float*)globs + off;
                    float4 f0 = ((const float4*)sf)[0];
                    float4 f1 = ((const float4*)sf)[1];
                    o[0]=(bf16)f0.x; o[1]=(bf16)f0.y; o[2]=(bf16)f0.z; o[3]=(bf16)f0.w;
                    o[4]=(bf16)f1.x; o[5]=(bf16)f1.y; o[6]=(bf16)f1.z; o[7]=(bf16)f1.w;
                }
                *(bf16x8*)&sX[e * SX_STR + c * 8] = o;
            }
        }
    }
    __syncthreads();

    const int w = t >> 6, lane = t & 63, quad = lane >> 4, l15 = lane & 15;
    f32x4 z = {0.f, 0.f, 0.f, 0.f};

    // Phase 2: GEMM1 X(48x352)@W1T(->256) + X@A1T(->64), B-frags double-buffered
    f32x4 acc[3][4], accA[3];
    #pragma unroll
    for (int s2 = 0; s2 < 3; s2++) { accA[s2] = z; for (int i = 0; i < 4; i++) acc[s2][i] = z; }
    {
        const bf16* pW = W1T + (size_t)(w * 64 + l15) * XD + quad * 8;
        const bf16* pA = A1T + (size_t)(w * 16 + l15) * XD + quad * 8;
        bf16x8 bw[4], ba;
        #pragma unroll
        for (int i = 0; i < 4; i++) bw[i] = *(const bf16x8*)(pW + (size_t)i * 16 * XD);
        ba = *(const bf16x8*)pA;
        for (int kk = 0; kk < 11; kk++) {
            bf16x8 bwn[4], ban;
            if (kk < 10) {
                #pragma unroll
                for (int i = 0; i < 4; i++) bwn[i] = *(const bf16x8*)(pW + (size_t)i * 16 * XD + (kk + 1) * 32);
                ban = *(const bf16x8*)(pA + (kk + 1) * 32);
            }
            const int kc = kk * 32 + quad * 8;
            bf16x8 a[3];
            #pragma unroll
            for (int s2 = 0; s2 < 3; s2++) a[s2] = *(bf16x8*)&sX[(s2 * 16 + l15) * SX_STR + kc];
            #pragma unroll
            for (int i = 0; i < 4; i++)
                #pragma unroll
                for (int s2 = 0; s2 < 3; s2++)
                    acc[s2][i] = __builtin_amdgcn_mfma_f32_16x16x32_bf16(a[s2], bw[i], acc[s2][i], 0, 0, 0);
            #pragma unroll
            for (int s2 = 0; s2 < 3; s2++)
                accA[s2] = __builtin_amdgcn_mfma_f32_16x16x32_bf16(a[s2], ba, accA[s2], 0, 0, 0);
            if (kk < 10) {
                #pragma unroll
                for (int i = 0; i < 4; i++) bw[i] = bwn[i];
                ba = ban;
            }
        }
    }
    __syncthreads();   // all sX reads done before overlay writes

    // Phase 3: epilogue -> sH (overlay) and sA (overlay)
    #pragma unroll
    for (int i = 0; i < 4; i++) {
        const int n = w * 64 + i * 16 + l15;
        const float bb = prm[PRM_B1 + n];
        #pragma unroll
        for (int s2 = 0; s2 < 3; s2++)
            #pragma unroll
            for (int r = 0; r < 4; r++)
                sH[(s2 * 16 + quad * 4 + r) * SH_STR + n] = (bf16)siluf(acc[s2][i][r] + bb);
    }
    {
        const int n = w * 16 + l15;
        const float ba1 = prm[PRM_AB1 + n];
        #pragma unroll
        for (int s2 = 0; s2 < 3; s2++)
            #pragma unroll
            for (int r = 0; r < 4; r++)
                sA[(s2 * 16 + quad * 4 + r) * SA_STR + n] = (bf16)siluf(accA[s2][r] + ba1);
    }
    __syncthreads();

    // Phase 4: scores = exp((silu(X@A1)@A2 + ab2)/8)  (no max-sub: |logit| << 1)
    if (t < TE * NHEADS) {
        const int e = t >> 2, h = t & 3;
        if (e < ne) {
            float dot = 0.f;
            #pragma unroll
            for (int c = 0; c < 8; c++) {
                bf16x8 vv = *(bf16x8*)&sA[e * SA_STR + c * 8];
                #pragma unroll
                for (int ii = 0; ii < 8; ii++)
                    dot += (float)vv[ii] * sA2[(c * 8 + ii) * NHEADS + h];
            }
            float ex = __expf((dot + prm[PRM_AB2 + h]) * 0.125f);
            sScore[e * 4 + h] = ex;
            atomicAdd(&denom[sSeg[e] * NHEADS + h], ex);
        }
    }
    __syncthreads();

    // Phase 5: GEMM2 H@W2T + b2 + edges0 -> new_edges; fused pooled atomics
    {
        f32x4 c2[3] = {z, z, z};
        const int n = w * 16 + l15;          // head = w
        const bf16* pW2 = W2T + (size_t)n * H1D + quad * 8;
        bf16x8 b2f = *(const bf16x8*)pW2;
        for (int kk = 0; kk < 8; kk++) {
            bf16x8 b2n;
            if (kk < 7) b2n = *(const bf16x8*)(pW2 + (kk + 1) * 32);
            const int kc = kk * 32 + quad * 8;
            #pragma unroll
            for (int s2 = 0; s2 < 3; s2++) {
                bf16x8 a = *(bf16x8*)&sH[(s2 * 16 + l15) * SH_STR + kc];
                c2[s2] = __builtin_amdgcn_mfma_f32_16x16x32_bf16(a, b2f, c2[s2], 0, 0, 0);
            }
            if (kk < 7) b2f = b2n;
        }
        const float bb2 = prm[PRM_B2 + n];
        #pragma unroll
        for (int s2 = 0; s2 < 3; s2++)
            #pragma unroll
            for (int r = 0; r < 4; r++) {
                const int row = s2 * 16 + quad * 4 + r;
                if (row < ne) {
                    size_t off = (size_t)(e0 + row) * EDIM + n;
                    float ev = isb ? (float)((const bf16*)edges0)[off] : ((const float*)edges0)[off];
                    float v = c2[s2][r] + bb2 + ev;
                    if (isb) ((bf16*)outNE)[off] = (bf16)v;
                    else     ((float*)outNE)[off] = v;
                    float ex = sScore[row * 4 + w];
                    atomicAdd(&pooled[(size_t)sSeg[row] * OUTD + n], v * ex);
                }
            }
    }
}

// ---------------- K_norm: pooled / denom -> d_out ----------------
__global__ __launch_bounds__(256) void k_norm(const float* __restrict__ pooled,
                                              const float* __restrict__ denom,
                                              const void* __restrict__ nodes,
                                              void* __restrict__ d_out) {
    int i = blockIdx.x * 256 + threadIdx.x;   // NSEG*OUTD = 262144
    bool isb = probe_bf16(nodes, threadIdx.x);
    int s = i >> 6, j = i & 63, h = j >> 4;
    float den = denom[s * 4 + h];
    float v = (den > 0.f) ? pooled[i] / den : 0.0f;
    size_t po = (size_t)E_TOT * OUTD + i;
    if (isb) ((bf16*)d_out)[po] = (bf16)v;
    else     ((float*)d_out)[po] = v;
}

static char* align_up(char* p, size_t a) {
    return (char*)(((uintptr_t)p + (a - 1)) & ~(uintptr_t)(a - 1));
}

extern "C" void kernel_launch(void* const* d_in, const int* in_sizes, int n_in,
                              void* d_out, int out_size, void* d_ws, size_t ws_size,
                              hipStream_t stream) {
    const void* nodes  = d_in[0];
    const void* edges0 = d_in[1];
    const void* globs  = d_in[2];
    const void* ln_g   = d_in[3];
    const void* ln_b   = d_in[4];
    const void* W1     = d_in[5];
    const void* b1     = d_in[6];
    const void* W2     = d_in[7];
    const void* b2     = d_in[8];
    const void* A1     = d_in[9];
    const void* ab1    = d_in[10];
    const void* A2     = d_in[11];
    const void* ab2    = d_in[12];
    const int*  bidx   = (const int*)d_in[13];
    const int*  sidx   = (const int*)d_in[14];
    const int*  ridx   = (const int*)d_in[15];

    char* p = (char*)d_ws;
    float*    prm    = (float*)p;    p = align_up(p + PRM_TOT * 4, 256);
    bf16*     W1T    = (bf16*)p;     p = align_up(p + XD * H1D * 2, 256);
    bf16*     W2T    = (bf16*)p;     p = align_up(p + H1D * OUTD * 2, 256);
    bf16*     A1T    = (bf16*)p;     p = align_up(p + XD * AHD * 2, 256);
    float*    denom  = (float*)p;    p += NSEG * NHEADS * 4;         // 64 KB
    float*    pooled = (float*)p;    p += (size_t)NSEG * OUTD * 4;   // 1 MB (contiguous w/ denom)

    k_prep<<<dim3(ZOFF + ZBLK), dim3(256), 0, stream>>>(
        nodes, W1, W2, A1, ln_g, ln_b, b1, b2, A2, ab1, ab2,
        W1T, W2T, A1T, prm, denom);
    k_edge<<<dim3((E_TOT + TE - 1) / TE), dim3(256), 0, stream>>>(
        nodes, edges0, globs, prm,
        bidx, sidx, ridx, W1T, W2T, A1T, d_out, denom, pooled);
    k_norm<<<dim3(NSEG * OUTD / 256), dim3(256), 0, stream>>>(pooled, denom, nodes, d_out);
}